// Round 3
// baseline (98.485 us; speedup 1.0000x reference)
//
#include <hip/hip_runtime.h>
#include <float.h>

#define BB 16
#define MM 32
#define KK 20
#define AA 8
#define TT 30
#define TD 60          // T*D floats per trajectory
#define NS 15          // float4 steps per trajectory (2 t-steps each)
#define S4 17          // padded row stride in float4 units (odd -> conflict-free with stride-5 k map)
#define KT 22          // target rows: 20 real + gt (row 20) + dummy (row 21)
#define PDS 23         // pd row stride in floats (odd)

// One block = 4 m's (one wave each) for a fixed (b, a).
// Per wave: 4x2 (k x kp) register tile; k = tk+5i (tk<5), kp = tkp+11j (tkp<11)
// -> 55 active lanes cover the 20x22 pair matrix (cols 20=gt, 21=dummy).
__global__ __launch_bounds__(256) void imle_part_kernel(
    const float* __restrict__ gen,   // B M K A T D
    const float* __restrict__ tgt,   // B K A T D
    const float* __restrict__ gt,    // B A T D
    float* __restrict__ ws_cham,     // [B][M][A]
    float* __restrict__ ws_gt)       // [B][M][A]
{
    __shared__ float4 sg[4][KK][S4];   // 4 m-slices of gen, scaled by 50
    __shared__ float4 st[KT][S4];      // target rows (x50) + gt row (metric) + dummy
    __shared__ float  pd[4][KK][PDS];  // per-m pairwise mean distances (cols 0..20 used)

    const int blk = blockIdx.x;        // grid = B*A*(M/4) = 1024
    const int mg = blk & 7;            // m-group (M/4 = 8)
    const int a  = (blk >> 3) & 7;
    const int b  = blk >> 6;
    const int m0 = mg * 4;
    const int tid = threadIdx.x;

    // ---- stage gen: 4m x 20k rows of 15 float4 ----
    for (int idx = tid; idx < 80 * NS; idx += 256) {
        int row = idx / NS, q = idx - row * NS;
        int mi = row / KK, k = row - mi * KK;
        const float4* src = (const float4*)(gen +
            (size_t)(((b * MM + m0 + mi) * KK + k) * AA + a) * TD);
        float4 v = src[q];
        v.x *= 50.f; v.y *= 50.f; v.z *= 50.f; v.w *= 50.f;
        sg[mi][k][q] = v;
    }
    // ---- stage target rows 0..19 (x50), row 20 = gt (metric), row 21 = zeros ----
    for (int idx = tid; idx < KT * NS; idx += 256) {
        int row = idx / NS, q = idx - row * NS;
        float4 v;
        if (row < KK) {
            v = ((const float4*)(tgt + (size_t)((b * KK + row) * AA + a) * TD))[q];
            v.x *= 50.f; v.y *= 50.f; v.z *= 50.f; v.w *= 50.f;
        } else if (row == KK) {
            v = ((const float4*)(gt + (size_t)(b * AA + a) * TD))[q];
        } else {
            v = make_float4(0.f, 0.f, 0.f, 0.f);
        }
        st[row][q] = v;
    }
    __syncthreads();

    const int w = tid >> 6;        // wave id -> m index offset
    const int lane = tid & 63;

    // ---- pairwise distances, 4x2 register tile over interleaved (k, kp) ----
    if (lane < 55) {
        const int tk  = lane / 11;       // 0..4  -> k  = tk + 5i
        const int tkp = lane - tk * 11;  // 0..10 -> kp = tkp + 11j
        float acc[4][2] = {{0.f, 0.f}, {0.f, 0.f}, {0.f, 0.f}, {0.f, 0.f}};
        for (int s = 0; s < NS; ++s) {
            float4 gv[4], tv[2];
#pragma unroll
            for (int i = 0; i < 4; ++i) gv[i] = sg[w][tk + 5 * i][s];
#pragma unroll
            for (int j = 0; j < 2; ++j) tv[j] = st[tkp + 11 * j][s];
#pragma unroll
            for (int i = 0; i < 4; ++i) {
#pragma unroll
                for (int j = 0; j < 2; ++j) {
                    float dx1 = gv[i].x - tv[j].x;
                    float dy1 = gv[i].y - tv[j].y;
                    float dx2 = gv[i].z - tv[j].z;
                    float dy2 = gv[i].w - tv[j].w;
                    acc[i][j] += __builtin_amdgcn_sqrtf(dx1 * dx1 + dy1 * dy1)
                               + __builtin_amdgcn_sqrtf(dx2 * dx2 + dy2 * dy2);
                }
            }
        }
        const float inv_t = 1.0f / TT;
#pragma unroll
        for (int i = 0; i < 4; ++i) {
#pragma unroll
            for (int j = 0; j < 2; ++j) {
                int kp = tkp + 11 * j;
                if (kp <= KK)  // col 21 is dummy, skip store
                    pd[w][tk + 5 * i][kp] = acc[i][j] * inv_t;
            }
        }
    }
    __syncthreads();

    // ---- row/col mins over real 20x20 + gt col, per wave / per m ----
    float v = 0.f;
    float dg = FLT_MAX;
    if (lane < KK) {
        float rm = pd[w][lane][0];
#pragma unroll
        for (int j = 1; j < KK; ++j) rm = fminf(rm, pd[w][lane][j]);
        float cm = pd[w][0][lane];
#pragma unroll
        for (int j = 1; j < KK; ++j) cm = fminf(cm, pd[w][j][lane]);
        v = rm + cm;
        dg = pd[w][lane][KK];   // gt column
    }
#pragma unroll
    for (int off = 16; off > 0; off >>= 1) {
        v += __shfl_xor(v, off, 32);
        dg = fminf(dg, __shfl_xor(dg, off, 32));
    }

    if (lane == 0) {
        const size_t o = ((size_t)b * MM + (m0 + w)) * AA + a;
        ws_cham[o] = v * (1.0f / KK);
        ws_gt[o]   = dg;
    }
}

// Single block: mean over A, min over M, mean over B, write 3 outputs.
__global__ __launch_bounds__(512) void imle_final_kernel(
    const float* __restrict__ ws_cham,
    const float* __restrict__ ws_gt,
    float* __restrict__ out)
{
    __shared__ float ch[BB * MM], gv[BB * MM];
    __shared__ float mch[BB], mgt[BB];
    const int tid = threadIdx.x;  // 512 == B*M
    const int b = tid / MM, m = tid % MM;

    float sc = 0.f, sg = 0.f;
#pragma unroll
    for (int a = 0; a < AA; ++a) {
        sc += ws_cham[((size_t)b * MM + m) * AA + a];
        sg += ws_gt[((size_t)b * MM + m) * AA + a];
    }
    ch[tid] = sc * (1.0f / AA);
    gv[tid] = sg * (1.0f / AA);
    __syncthreads();

    if (tid < BB) {
        float c = ch[tid * MM], g = gv[tid * MM];
        for (int j = 1; j < MM; ++j) {
            c = fminf(c, ch[tid * MM + j]);
            g = fminf(g, gv[tid * MM + j]);
        }
        mch[tid] = c;
        mgt[tid] = g;
    }
    __syncthreads();

    if (tid == 0) {
        float lc = 0.f, lg = 0.f;
        for (int j = 0; j < BB; ++j) { lc += mch[j]; lg += mgt[j]; }
        lc *= (1.0f / BB);
        lg *= (1.0f / BB);
        out[0] = lc + lg;
        out[1] = lc;
        out[2] = lg;
    }
}

extern "C" void kernel_launch(void* const* d_in, const int* in_sizes, int n_in,
                              void* d_out, int out_size, void* d_ws, size_t ws_size,
                              hipStream_t stream) {
    const float* gen = (const float*)d_in[0];
    const float* tgt = (const float*)d_in[1];
    const float* gt  = (const float*)d_in[2];
    float* ws_cham = (float*)d_ws;                 // B*M*A floats
    float* ws_gt   = ws_cham + BB * MM * AA;       // B*M*A floats
    float* out     = (float*)d_out;

    imle_part_kernel<<<BB * AA * (MM / 4), 256, 0, stream>>>(gen, tgt, gt, ws_cham, ws_gt);
    imle_final_kernel<<<1, 512, 0, stream>>>(ws_cham, ws_gt, out);
}

// Round 4
// 87.100 us; speedup vs baseline: 1.1307x; 1.1307x over previous
//
#include <hip/hip_runtime.h>
#include <float.h>

#define BB 16
#define MM 32
#define KK 20
#define AA 8
#define TT 30
#define TD 60          // T*D floats per trajectory
#define NS 15          // float4 steps per trajectory (2 t-steps each)
#define S4 17          // padded row stride in float4 units (odd)
#define KT 22          // target rows: 20 real + gt (row 20) + dummy (row 21)
#define PDS 23         // pd row stride in floats (odd)

// One block = one wave = one (b, a, m).  grid = B*A*M = 4096.
// 4x2 (k x kp) register tile; k = tk+5i (tk<5), kp = tkp+11j (tkp<11)
// -> 55 active lanes cover the 20x22 pair matrix (col 20=gt, 21=dummy).
// __launch_bounds__(64,4): cap VGPR at 128 -> 4 waves/SIMD -> 16 blocks/CU
// -> all 4096 blocks co-resident.
__global__ __launch_bounds__(64, 4) void imle_part_kernel(
    const float* __restrict__ gen,   // B M K A T D
    const float* __restrict__ tgt,   // B K A T D
    const float* __restrict__ gt,    // B A T D
    float* __restrict__ ws_cham,     // [B][M][A]
    float* __restrict__ ws_gt)       // [B][M][A]
{
    __shared__ float4 sg[KK][S4];    // gen slice, scaled by 50
    __shared__ float4 st[KT][S4];    // target rows (x50) + gt row (metric) + dummy
    __shared__ float  pd[KK][PDS];   // pairwise mean distances (cols 0..20 used)

    const int blk = blockIdx.x;      // b*A*M + a*M + m? choose: blk = ((b*AA)+a)*MM + m
    const int m = blk & 31;
    const int a = (blk >> 5) & 7;
    const int b = blk >> 8;
    const int lane = threadIdx.x;

    // ---- stage gen: 20 rows x 15 float4 (row k is 60 contiguous floats) ----
    const float* gbase = gen + (size_t)(((b * MM + m) * KK) * AA + a) * TD;
    for (int idx = lane; idx < KK * NS; idx += 64) {
        int k = idx / NS, q = idx - k * NS;
        float4 v = ((const float4*)(gbase + (size_t)k * AA * TD))[q];
        v.x *= 50.f; v.y *= 50.f; v.z *= 50.f; v.w *= 50.f;
        sg[k][q] = v;
    }
    // ---- stage target rows 0..19 (x50), row 20 = gt (metric), row 21 = zeros ----
    for (int idx = lane; idx < KT * NS; idx += 64) {
        int row = idx / NS, q = idx - row * NS;
        float4 v;
        if (row < KK) {
            v = ((const float4*)(tgt + (size_t)((b * KK + row) * AA + a) * TD))[q];
            v.x *= 50.f; v.y *= 50.f; v.z *= 50.f; v.w *= 50.f;
        } else if (row == KK) {
            v = ((const float4*)(gt + (size_t)(b * AA + a) * TD))[q];
        } else {
            v = make_float4(0.f, 0.f, 0.f, 0.f);
        }
        st[row][q] = v;
    }
    __syncthreads();

    // ---- pairwise distances, 4x2 register tile over interleaved (k, kp) ----
    if (lane < 55) {
        const int tk  = lane / 11;       // 0..4  -> k  = tk + 5i
        const int tkp = lane - tk * 11;  // 0..10 -> kp = tkp + 11j
        float acc[4][2] = {{0.f, 0.f}, {0.f, 0.f}, {0.f, 0.f}, {0.f, 0.f}};
#pragma unroll 3
        for (int s = 0; s < NS; ++s) {
            float4 gv[4], tv[2];
#pragma unroll
            for (int i = 0; i < 4; ++i) gv[i] = sg[tk + 5 * i][s];
#pragma unroll
            for (int j = 0; j < 2; ++j) tv[j] = st[tkp + 11 * j][s];
#pragma unroll
            for (int i = 0; i < 4; ++i) {
#pragma unroll
                for (int j = 0; j < 2; ++j) {
                    float dx1 = gv[i].x - tv[j].x;
                    float dy1 = gv[i].y - tv[j].y;
                    float dx2 = gv[i].z - tv[j].z;
                    float dy2 = gv[i].w - tv[j].w;
                    acc[i][j] += __builtin_amdgcn_sqrtf(dx1 * dx1 + dy1 * dy1)
                               + __builtin_amdgcn_sqrtf(dx2 * dx2 + dy2 * dy2);
                }
            }
        }
        const float inv_t = 1.0f / TT;
#pragma unroll
        for (int i = 0; i < 4; ++i) {
#pragma unroll
            for (int j = 0; j < 2; ++j) {
                int kp = tkp + 11 * j;
                if (kp <= KK)  // col 21 is dummy, skip store
                    pd[tk + 5 * i][kp] = acc[i][j] * inv_t;
            }
        }
    }
    __syncthreads();

    // ---- row/col mins over 20x20 + gt col ----
    float v = 0.f;
    float dg = FLT_MAX;
    if (lane < KK) {
        float rm = pd[lane][0];
#pragma unroll
        for (int j = 1; j < KK; ++j) rm = fminf(rm, pd[lane][j]);
        float cm = pd[0][lane];
#pragma unroll
        for (int j = 1; j < KK; ++j) cm = fminf(cm, pd[j][lane]);
        v = rm + cm;
        dg = pd[lane][KK];   // gt column
    }
#pragma unroll
    for (int off = 16; off > 0; off >>= 1) {
        v += __shfl_xor(v, off, 32);
        dg = fminf(dg, __shfl_xor(dg, off, 32));
    }

    if (lane == 0) {
        const size_t o = ((size_t)b * MM + m) * AA + a;
        ws_cham[o] = v * (1.0f / KK);
        ws_gt[o]   = dg;
    }
}

// Single block: mean over A, min over M, mean over B, write 3 outputs.
__global__ __launch_bounds__(512) void imle_final_kernel(
    const float* __restrict__ ws_cham,
    const float* __restrict__ ws_gt,
    float* __restrict__ out)
{
    __shared__ float ch[BB * MM], gv[BB * MM];
    __shared__ float mch[BB], mgt[BB];
    const int tid = threadIdx.x;  // 512 == B*M
    const int b = tid / MM, m = tid % MM;

    float sc = 0.f, sg = 0.f;
#pragma unroll
    for (int a = 0; a < AA; ++a) {
        sc += ws_cham[((size_t)b * MM + m) * AA + a];
        sg += ws_gt[((size_t)b * MM + m) * AA + a];
    }
    ch[tid] = sc * (1.0f / AA);
    gv[tid] = sg * (1.0f / AA);
    __syncthreads();

    if (tid < BB) {
        float c = ch[tid * MM], g = gv[tid * MM];
        for (int j = 1; j < MM; ++j) {
            c = fminf(c, ch[tid * MM + j]);
            g = fminf(g, gv[tid * MM + j]);
        }
        mch[tid] = c;
        mgt[tid] = g;
    }
    __syncthreads();

    if (tid == 0) {
        float lc = 0.f, lg = 0.f;
        for (int j = 0; j < BB; ++j) { lc += mch[j]; lg += mgt[j]; }
        lc *= (1.0f / BB);
        lg *= (1.0f / BB);
        out[0] = lc + lg;
        out[1] = lc;
        out[2] = lg;
    }
}

extern "C" void kernel_launch(void* const* d_in, const int* in_sizes, int n_in,
                              void* d_out, int out_size, void* d_ws, size_t ws_size,
                              hipStream_t stream) {
    const float* gen = (const float*)d_in[0];
    const float* tgt = (const float*)d_in[1];
    const float* gt  = (const float*)d_in[2];
    float* ws_cham = (float*)d_ws;                 // B*M*A floats
    float* ws_gt   = ws_cham + BB * MM * AA;       // B*M*A floats
    float* out     = (float*)d_out;

    imle_part_kernel<<<BB * AA * MM, 64, 0, stream>>>(gen, tgt, gt, ws_cham, ws_gt);
    imle_final_kernel<<<1, 512, 0, stream>>>(ws_cham, ws_gt, out);
}

// Round 5
// 81.811 us; speedup vs baseline: 1.2038x; 1.0646x over previous
//
#include <hip/hip_runtime.h>
#include <float.h>

#define BB 16
#define MM 32
#define KK 20
#define AA 8
#define TT 30
#define TD 60          // T*D floats per trajectory
#define NS 15          // float4 steps per trajectory (2 t-steps each)
#define KT 22          // target rows: 20 real + gt (row 20) + dummy (row 21)
#define PDS 21         // pd row stride in floats (odd, gcd(21,32)=1 -> conflict-free scans)

// One block = 4 waves = 4 m's sharing the target tile, for a fixed (b, a).
// grid = B*A*(M/4) = 1024.
// Per wave: 4x2 (k x kp) register tile; k = tk+5i (tk<5), kp = tkp+11j (tkp<11)
// -> 55 active lanes cover the 20x22 pair matrix (col 20=gt, 21=dummy).
// LDS ~31.2 KB -> 5 blocks/CU; __launch_bounds__(256,5) caps VGPR ~102
// -> 20 waves/CU (R3 was VGPR-limited to 8).
__global__ __launch_bounds__(256, 5) void imle_part_kernel(
    const float* __restrict__ gen,   // B M K A T D
    const float* __restrict__ tgt,   // B K A T D
    const float* __restrict__ gt,    // B A T D
    float* __restrict__ ws_cham,     // [B][M][A]
    float* __restrict__ ws_gt)       // [B][M][A]
{
    __shared__ float4 sg[4][KK][NS];   // 4 m-slices of gen, x50 (no pad: stride-5 k-map is conflict-free)
    __shared__ float4 st[KT][NS];      // target rows (x50) + gt row (metric) + dummy
    __shared__ float  pd[4][KK][PDS];  // per-m pairwise mean distances (cols 0..20 used)

    const int blk = blockIdx.x;        // grid = 1024
    const int mg = blk & 7;            // m-group (M/4 = 8)
    const int a  = (blk >> 3) & 7;
    const int b  = blk >> 6;
    const int m0 = mg * 4;
    const int tid = threadIdx.x;

    // ---- stage gen: 4m x 20k rows of 15 float4 ----
    for (int idx = tid; idx < 80 * NS; idx += 256) {
        int row = idx / NS, q = idx - row * NS;
        int mi = row / KK, k = row - mi * KK;
        const float4* src = (const float4*)(gen +
            (size_t)(((b * MM + m0 + mi) * KK + k) * AA + a) * TD);
        float4 v = src[q];
        v.x *= 50.f; v.y *= 50.f; v.z *= 50.f; v.w *= 50.f;
        sg[mi][k][q] = v;
    }
    // ---- stage target rows 0..19 (x50), row 20 = gt (metric), row 21 = zeros ----
    for (int idx = tid; idx < KT * NS; idx += 256) {
        int row = idx / NS, q = idx - row * NS;
        float4 v;
        if (row < KK) {
            v = ((const float4*)(tgt + (size_t)((b * KK + row) * AA + a) * TD))[q];
            v.x *= 50.f; v.y *= 50.f; v.z *= 50.f; v.w *= 50.f;
        } else if (row == KK) {
            v = ((const float4*)(gt + (size_t)(b * AA + a) * TD))[q];
        } else {
            v = make_float4(0.f, 0.f, 0.f, 0.f);
        }
        st[row][q] = v;
    }
    __syncthreads();

    const int w = tid >> 6;        // wave id -> m index offset
    const int lane = tid & 63;

    // ---- pairwise distances, 4x2 register tile over interleaved (k, kp) ----
    if (lane < 55) {
        const int tk  = lane / 11;       // 0..4  -> k  = tk + 5i
        const int tkp = lane - tk * 11;  // 0..10 -> kp = tkp + 11j
        float acc[4][2] = {{0.f, 0.f}, {0.f, 0.f}, {0.f, 0.f}, {0.f, 0.f}};
#pragma unroll 1
        for (int s = 0; s < NS; ++s) {
            float4 gv[4], tv[2];
#pragma unroll
            for (int i = 0; i < 4; ++i) gv[i] = sg[w][tk + 5 * i][s];
#pragma unroll
            for (int j = 0; j < 2; ++j) tv[j] = st[tkp + 11 * j][s];
#pragma unroll
            for (int i = 0; i < 4; ++i) {
#pragma unroll
                for (int j = 0; j < 2; ++j) {
                    float dx1 = gv[i].x - tv[j].x;
                    float dy1 = gv[i].y - tv[j].y;
                    float dx2 = gv[i].z - tv[j].z;
                    float dy2 = gv[i].w - tv[j].w;
                    acc[i][j] += __builtin_amdgcn_sqrtf(dx1 * dx1 + dy1 * dy1)
                               + __builtin_amdgcn_sqrtf(dx2 * dx2 + dy2 * dy2);
                }
            }
        }
        const float inv_t = 1.0f / TT;
#pragma unroll
        for (int i = 0; i < 4; ++i) {
#pragma unroll
            for (int j = 0; j < 2; ++j) {
                int kp = tkp + 11 * j;
                if (kp <= KK)  // col 21 is dummy, skip store
                    pd[w][tk + 5 * i][kp] = acc[i][j] * inv_t;
            }
        }
    }
    __syncthreads();

    // ---- row/col mins over 20x20 + gt col, per wave / per m ----
    float v = 0.f;
    float dg = FLT_MAX;
    if (lane < KK) {
        float rm = pd[w][lane][0];
#pragma unroll
        for (int j = 1; j < KK; ++j) rm = fminf(rm, pd[w][lane][j]);
        float cm = pd[w][0][lane];
#pragma unroll
        for (int j = 1; j < KK; ++j) cm = fminf(cm, pd[w][j][lane]);
        v = rm + cm;
        dg = pd[w][lane][KK];   // gt column
    }
#pragma unroll
    for (int off = 16; off > 0; off >>= 1) {
        v += __shfl_xor(v, off, 32);
        dg = fminf(dg, __shfl_xor(dg, off, 32));
    }

    if (lane == 0) {
        const size_t o = ((size_t)b * MM + (m0 + w)) * AA + a;
        ws_cham[o] = v * (1.0f / KK);
        ws_gt[o]   = dg;
    }
}

// Single block: mean over A, min over M, mean over B, write 3 outputs.
__global__ __launch_bounds__(512) void imle_final_kernel(
    const float* __restrict__ ws_cham,
    const float* __restrict__ ws_gt,
    float* __restrict__ out)
{
    __shared__ float ch[BB * MM], gv[BB * MM];
    __shared__ float mch[BB], mgt[BB];
    const int tid = threadIdx.x;  // 512 == B*M
    const int b = tid / MM, m = tid % MM;

    float sc = 0.f, sg = 0.f;
#pragma unroll
    for (int a = 0; a < AA; ++a) {
        sc += ws_cham[((size_t)b * MM + m) * AA + a];
        sg += ws_gt[((size_t)b * MM + m) * AA + a];
    }
    ch[tid] = sc * (1.0f / AA);
    gv[tid] = sg * (1.0f / AA);
    __syncthreads();

    if (tid < BB) {
        float c = ch[tid * MM], g = gv[tid * MM];
        for (int j = 1; j < MM; ++j) {
            c = fminf(c, ch[tid * MM + j]);
            g = fminf(g, gv[tid * MM + j]);
        }
        mch[tid] = c;
        mgt[tid] = g;
    }
    __syncthreads();

    if (tid == 0) {
        float lc = 0.f, lg = 0.f;
        for (int j = 0; j < BB; ++j) { lc += mch[j]; lg += mgt[j]; }
        lc *= (1.0f / BB);
        lg *= (1.0f / BB);
        out[0] = lc + lg;
        out[1] = lc;
        out[2] = lg;
    }
}

extern "C" void kernel_launch(void* const* d_in, const int* in_sizes, int n_in,
                              void* d_out, int out_size, void* d_ws, size_t ws_size,
                              hipStream_t stream) {
    const float* gen = (const float*)d_in[0];
    const float* tgt = (const float*)d_in[1];
    const float* gt  = (const float*)d_in[2];
    float* ws_cham = (float*)d_ws;                 // B*M*A floats
    float* ws_gt   = ws_cham + BB * MM * AA;       // B*M*A floats
    float* out     = (float*)d_out;

    imle_part_kernel<<<BB * AA * (MM / 4), 256, 0, stream>>>(gen, tgt, gt, ws_cham, ws_gt);
    imle_final_kernel<<<1, 512, 0, stream>>>(ws_cham, ws_gt, out);
}